// Round 1
// 294.239 us; speedup vs baseline: 1.0171x; 1.0171x over previous
//
#include <hip/hip_runtime.h>

typedef __bf16 bf16;
typedef bf16 bf16x8 __attribute__((ext_vector_type(8)));
typedef float f32x4 __attribute__((ext_vector_type(4)));
typedef float f32x16 __attribute__((ext_vector_type(16)));
typedef int i32x2 __attribute__((ext_vector_type(2)));

#define B_   4
#define N_   2048
#define DIM_ 1024
#define H_   16
#define DH_  64
#define M_   (B_ * N_)   // 8192

// log2(e) * (1/sqrt(64))
#define CEXP 0.18033688f

#define GLOBAL_CP(g) (const __attribute__((address_space(1))) void*)(g)
#define LDS_CP(l)    (__attribute__((address_space(3))) void*)(l)

// ---------------------------------------------------------------------------
// fused fp32 -> bf16 conversion for x | wqkv | wproj (contiguous dest in ws).
// ---------------------------------------------------------------------------
__global__ __launch_bounds__(256) void cvt_all(
    const float* __restrict__ x, const float* __restrict__ wq,
    const float* __restrict__ wp, bf16* __restrict__ o,
    int nx4, int nwq4, int nwp4)
{
    const int i = blockIdx.x * blockDim.x + threadIdx.x;
    const float* src; int si;
    if (i < nx4)                { src = x;  si = i; }
    else if (i < nx4 + nwq4)    { src = wq; si = i - nx4; }
    else                        { src = wp; si = i - nx4 - nwq4; }
    const float4 v = ((const float4*)src)[si];
    union { bf16 h[4]; uint2 u; } r;
    r.h[0] = (bf16)v.x; r.h[1] = (bf16)v.y;
    r.h[2] = (bf16)v.z; r.h[3] = (bf16)v.w;
    ((uint2*)o)[i] = r.u;
}

// ---------------------------------------------------------------------------
// GEMM (unchanged): BK=64, DMA staging, XOR source-swizzled chunks.
// mode 0: fp32 C row-major; mode 1: scatter q/k [bh][n][d] (Q pre-scaled) +
// V transposed [bh][d][n].
// ---------------------------------------------------------------------------
__global__ __launch_bounds__(256) void gemm_bt(
    const bf16* __restrict__ A, const bf16* __restrict__ Bm,
    int Ndim, int K, int mode,
    float* __restrict__ outf,
    bf16* __restrict__ qb, bf16* __restrict__ kbv, bf16* __restrict__ vbT)
{
    __shared__ bf16 As[128 * 64];   // 16384 B
    __shared__ bf16 Bs[128 * 64];   // 16384 B

    const int tid  = threadIdx.x;
    const int wave = tid >> 6;
    const int lane = tid & 63;
    const int quad = lane >> 4;
    const int lr   = lane & 15;
    const int wr   = wave >> 1, wc = wave & 1;
    const int m0 = blockIdx.y * 128;
    const int n0 = blockIdx.x * 128;

    f32x4 acc[4][4];
#pragma unroll
    for (int i = 0; i < 4; i++)
#pragma unroll
        for (int j = 0; j < 4; j++) acc[i][j] = f32x4{0.f, 0.f, 0.f, 0.f};

    const int sl8 = lane >> 3;
    const int sc8 = ((lane & 7) ^ (sl8 & 7)) * 8;

    for (int k0 = 0; k0 < K; k0 += 64) {
        __syncthreads();  // prev-iter frag reads done
#pragma unroll
        for (int c = 0; c < 4; c++) {
            const int ii  = wave * 4 + c;
            const int row = ii * 8 + sl8;
            __builtin_amdgcn_global_load_lds(
                GLOBAL_CP(A + (size_t)(m0 + row) * K + k0 + sc8),
                LDS_CP(&As[ii * 512 + lane * 8]), 16, 0, 0);
            __builtin_amdgcn_global_load_lds(
                GLOBAL_CP(Bm + (size_t)(n0 + row) * K + k0 + sc8),
                LDS_CP(&Bs[ii * 512 + lane * 8]), 16, 0, 0);
        }
        __syncthreads();  // staging visible (vmcnt drain)

#pragma unroll
        for (int s = 0; s < 2; s++) {
            bf16x8 af[4], bfr[4];
#pragma unroll
            for (int i = 0; i < 4; i++) {
                const int R = wr * 64 + i * 16 + lr;
                af[i] = *(const bf16x8*)(&As[R * 64 + (((s * 4 + quad) ^ (R & 7)) << 3)]);
            }
#pragma unroll
            for (int j = 0; j < 4; j++) {
                const int R = wc * 64 + j * 16 + lr;
                bfr[j] = *(const bf16x8*)(&Bs[R * 64 + (((s * 4 + quad) ^ (R & 7)) << 3)]);
            }
#pragma unroll
            for (int i = 0; i < 4; i++)
#pragma unroll
                for (int j = 0; j < 4; j++)
                    acc[i][j] = __builtin_amdgcn_mfma_f32_16x16x32_bf16(
                        af[i], bfr[j], acc[i][j], 0, 0, 0);
        }
    }

#pragma unroll
    for (int i = 0; i < 4; i++) {
        const int mbase = m0 + wr * 64 + i * 16 + quad * 4;
#pragma unroll
        for (int j = 0; j < 4; j++) {
            const int n = n0 + wc * 64 + j * 16 + lr;
            if (mode == 0) {
#pragma unroll
                for (int r = 0; r < 4; r++)
                    outf[(size_t)(mbase + r) * Ndim + n] = acc[i][j][r];
            } else {
                const int which = n >> 10;
                const int h = (n >> 6) & 15;
                const int d = n & 63;
                const int b  = mbase >> 11;
                const int t0 = mbase & 2047;
                if (which == 2) {
                    union { uint2 u; bf16 hh[4]; } p;
#pragma unroll
                    for (int r = 0; r < 4; r++) p.hh[r] = (bf16)acc[i][j][r];
                    *(uint2*)(&vbT[(((size_t)(b * 16 + h)) * 64 + d) * 2048 + t0]) = p.u;
                } else {
                    bf16* dst = (which == 0) ? qb : kbv;
                    const float sc = (which == 0) ? CEXP : 1.0f;
#pragma unroll
                    for (int r = 0; r < 4; r++)
                        dst[(((size_t)(b * 16 + h)) * 2048 + t0 + r) * 64 + d] =
                            (bf16)(acc[i][j][r] * sc);
                }
            }
        }
    }
}

// ---------------------------------------------------------------------------
// Flash attention v12:
//  - half-wave exchange via v_permlane32_swap_b32: one swap yields BOTH output
//    dwords (A' = {own.lo | partner.lo}, B' = {partner.hi | own.hi}), so 4
//    permlanes replace 4 ds_bpermute shuffles + 8 v_cndmask selects and take
//    the exchange off the LDS pipe.
//  - row-sum via ones-B MFMA into sacc (matrix pipe is 22% busy, VALU is the
//    bottleneck): kills 16 VALU adds per 32-key block, the per-tile
//    __shfl_xor(ssum), and all 16 epilogue __shfl(linv) — sacc[r] has the
//    same reg->q-row mapping as oacc so 1/sacc[r] is directly usable.
//  - __launch_bounds__(256,4): 4 blocks/CU (was 3); VGPR cap 128, LDS 128KB.
// ---------------------------------------------------------------------------
__global__ __launch_bounds__(256, 4) void attn_kernel(
    const bf16* __restrict__ qb, const bf16* __restrict__ kb,
    const bf16* __restrict__ vbT, bf16* __restrict__ ao)
{
    __shared__ bf16 Ks[128 * 64];   // 16384 B  [key][d], chunk-swizzled
    __shared__ bf16 Vs[64 * 128];   // 16384 B  [d][key], chunk-swizzled

    const int tid  = threadIdx.x;
    const int wave = tid >> 6;
    const int lane = tid & 63;
    const int l31  = lane & 31;
    const int hh   = lane >> 5;       // half-wave index

    // XCD swizzle: one head's 16 q-tiles on one XCD
    const int bid = blockIdx.x;
    const int qt  = (bid >> 3) & 15;
    const int bh  = ((bid >> 7) << 3) | (bid & 7);

    const bf16* Q  = qb  + (size_t)bh * N_ * DH_;
    const bf16* Kp = kb  + (size_t)bh * N_ * DH_;
    const bf16* Vp = vbT + (size_t)bh * DH_ * N_;   // [d][n]

    // Q B-frags: B[q=l31][d = ks*16 + hh*8 + j], loaded once from global
    bf16x8 qf[4];
#pragma unroll
    for (int ks = 0; ks < 4; ks++)
        qf[ks] = *(const bf16x8*)(Q + (size_t)(qt * 128 + wave * 32 + l31) * DH_
                                    + ks * 16 + hh * 8);

    bf16x8 onesb;
#pragma unroll
    for (int j = 0; j < 8; j++) onesb[j] = (bf16)1.0f;

    const int krow0 = (lane >> 3);
    const int kscol = ((lane & 7) ^ ((lane >> 3) & 7)) * 8;
    const int vrow0 = (lane >> 4);

    f32x16 oacc[2];
    f32x16 sacc;
#pragma unroll
    for (int r = 0; r < 16; r++) { oacc[0][r] = 0.f; oacc[1][r] = 0.f; sacc[r] = 0.f; }

    for (int t = 0; t < N_ / 128; t++) {
        __syncthreads();   // A: prev-iter Ks/Vs readers done
        // DMA-stage K tile (16 KB) and V tile (16 KB)
#pragma unroll
        for (int c = 0; c < 4; c++) {
            const int ii = wave * 4 + c;
            const int krow = ii * 8 + krow0;
            __builtin_amdgcn_global_load_lds(
                GLOBAL_CP(Kp + (size_t)(t * 128 + krow) * DH_ + kscol),
                LDS_CP(&Ks[ii * 512 + lane * 8]), 16, 0, 0);
            const int vrow = ii * 4 + vrow0;
            const int vscol = ((lane & 15) ^ (vrow & 15)) * 8;
            __builtin_amdgcn_global_load_lds(
                GLOBAL_CP(Vp + (size_t)vrow * N_ + t * 128 + vscol),
                LDS_CP(&Vs[ii * 512 + lane * 8]), 16, 0, 0);
        }
        __syncthreads();   // B: staging visible (compiler drains vmcnt)

#pragma unroll
        for (int kbk = 0; kbk < 4; kbk++) {      // 32-key blocks
            // S^T = K Q^T : D[key][q], key-rows kbk*32..+31
            f32x16 e;
#pragma unroll
            for (int r = 0; r < 16; r++) e[r] = 0.f;
#pragma unroll
            for (int ks = 0; ks < 4; ks++) {
                const int R  = kbk * 32 + l31;
                const int ch = ks * 2 + hh;               // 16B chunk index
                bf16x8 ak = *(const bf16x8*)(&Ks[R * 64 + ((ch ^ (R & 7)) << 3)]);
                e = __builtin_amdgcn_mfma_f32_32x32x16_bf16(ak, qf[ks], e, 0, 0, 0);
            }

            // softmax exponentials (row-sum comes from the ones-MFMA below)
#pragma unroll
            for (int r = 0; r < 16; r++) e[r] = exp2f(e[r]);

            // pack C/D-adjacent pairs into bf16x2 dwords (A-frag dword pairs):
            // g[m] covers keys base(m)+4*hh+{0,1}, base = (m&1)*2 + (m>>1)*8
            uint g[8];
#pragma unroll
            for (int m = 0; m < 8; m++) {
                union { uint u; bf16 h2[2]; } pk;
                pk.h2[0] = (bf16)e[2 * m];
                pk.h2[1] = (bf16)e[2 * m + 1];
                g[m] = pk.u;
            }

            // half-wave exchange: v_permlane32_swap_b32 swaps hi(A) <-> lo(B).
            // A' = {A.lo | B.lo}, B' = {A.hi | B.hi} (lane-local view:
            // A' = own-lo / partner-lo, B' = partner-hi / own-hi) — each swap
            // directly yields two A-frag dwords for BOTH half-waves.
            const i32x2 s0 = __builtin_amdgcn_permlane32_swap((int)g[0], (int)g[2], false, false);
            const i32x2 s1 = __builtin_amdgcn_permlane32_swap((int)g[1], (int)g[3], false, false);
            const i32x2 s2 = __builtin_amdgcn_permlane32_swap((int)g[4], (int)g[6], false, false);
            const i32x2 s3 = __builtin_amdgcn_permlane32_swap((int)g[5], (int)g[7], false, false);

            union { uint u[4]; bf16x8 v; } p0u, p1u;
            p0u.u[0] = (uint)s0[0];   // keys hh*8 + {0,1}
            p0u.u[1] = (uint)s1[0];   // keys hh*8 + {2,3}
            p0u.u[2] = (uint)s0[1];   // keys hh*8 + {4,5}
            p0u.u[3] = (uint)s1[1];   // keys hh*8 + {6,7}
            p1u.u[0] = (uint)s2[0];   // keys 16 + hh*8 + {0,1}
            p1u.u[1] = (uint)s3[0];
            p1u.u[2] = (uint)s2[1];
            p1u.u[3] = (uint)s3[1];

            // row sums on the matrix pipe: D[q][*] += sum_k P[q][k] * 1
            sacc = __builtin_amdgcn_mfma_f32_32x32x16_bf16(p0u.v, onesb, sacc, 0, 0, 0);
            sacc = __builtin_amdgcn_mfma_f32_32x32x16_bf16(p1u.v, onesb, sacc, 0, 0, 0);

            // O += P V : D[q][d], B = V^T[d=l31][key]
#pragma unroll
            for (int dblk = 0; dblk < 2; dblk++) {
                const int R   = dblk * 32 + l31;
                const int ch0 = kbk * 4 + hh;
                const int ch1 = kbk * 4 + 2 + hh;
                bf16x8 bv0 = *(const bf16x8*)(&Vs[R * 128 + ((ch0 ^ (R & 15)) << 3)]);
                bf16x8 bv1 = *(const bf16x8*)(&Vs[R * 128 + ((ch1 ^ (R & 15)) << 3)]);
                oacc[dblk] = __builtin_amdgcn_mfma_f32_32x32x16_bf16(p0u.v, bv0, oacc[dblk], 0, 0, 0);
                oacc[dblk] = __builtin_amdgcn_mfma_f32_32x32x16_bf16(p1u.v, bv1, oacc[dblk], 0, 0, 0);
            }
        }
    }

    // epilogue: O row q=(r&3)+8*(r>>2)+4*hh, col d=dblk*32+l31.
    // sacc[r] holds the full row sum for the SAME q-row in every lane.
    const int head = bh & 15;
    const int b    = bh >> 4;
#pragma unroll
    for (int r = 0; r < 16; r++) {
        const int qr  = (r & 3) + 8 * (r >> 2) + 4 * hh;
        const float inv = 1.0f / sacc[r];
        const int qrow = qt * 128 + wave * 32 + qr;
#pragma unroll
        for (int dblk = 0; dblk < 2; dblk++)
            ao[((size_t)(b * 2048 + qrow)) * 1024 + head * 64 + dblk * 32 + l31] =
                (bf16)(oacc[dblk][r] * inv);
    }
}

// ---------------------------------------------------------------------------
extern "C" void kernel_launch(void* const* d_in, const int* in_sizes, int n_in,
                              void* d_out, int out_size, void* d_ws, size_t ws_size,
                              hipStream_t stream)
{
    const float* x     = (const float*)d_in[0];   // [8192 x 1024] fp32
    const float* wqkv  = (const float*)d_in[1];   // [3072 x 1024] fp32
    const float* wproj = (const float*)d_in[2];   // [1024 x 1024] fp32
    float* out = (float*)d_out;                   // [8192 x 1024] fp32

    const size_t nx  = (size_t)M_ * DIM_;
    const size_t nwq = (size_t)3 * DIM_ * DIM_;
    const size_t nwp = (size_t)DIM_ * DIM_;
    const size_t seg = (size_t)B_ * H_ * N_ * DH_;

    bf16* xb     = (bf16*)d_ws;        // dead after QKV gemm; ao overlays it
    bf16* wqkvb  = xb + nx;            // contiguous with xb (cvt_all dest)
    bf16* wprojb = wqkvb + nwq;
    bf16* qb     = wprojb + nwp;
    bf16* kb     = qb + seg;
    bf16* vbT    = kb + seg;           // [bh][d][n]
    bf16* ao     = xb;

    const int nx4  = (int)(nx / 4), nwq4 = (int)(nwq / 4), nwp4 = (int)(nwp / 4);
    cvt_all<<<(nx4 + nwq4 + nwp4) / 256, 256, 0, stream>>>(
        x, wqkv, wproj, xb, nx4, nwq4, nwp4);

    gemm_bt<<<dim3(24, 64), 256, 0, stream>>>(xb, wqkvb, 3 * DIM_, DIM_, 1,
                                              nullptr, qb, kb, vbT);
    attn_kernel<<<dim3(1024), 256, 0, stream>>>(qb, kb, vbT, ao);
    gemm_bt<<<dim3(8, 64), 256, 0, stream>>>(ao, wprojb, DIM_, DIM_, 0,
                                             out, nullptr, nullptr, nullptr);
}